// Round 8
// baseline (583.802 us; speedup 1.0000x reference)
//
#include <hip/hip_runtime.h>

// FSMN depthwise strided FIR — R8: dual-ring (x 64-row + filt 12-row) LDS,
// 76 KB -> 2 blocks/CU co-residency. B=32, T=2000, D=512, L=R=20, stride 2.
//
// R7 post-mortem: 125us, VALU 25%, occ 9.4%. Win confirmed the serial
// global-filter + dist-1 DMA theory. Remaining cost: 105 KB LDS -> 1
// block/CU = 1 wave/SIMD; ~14k of 19k per-block cycles are bare latency
// (ds_read, 4 barrier drains, block skew) with nothing co-resident to
// hide them. R8 shrinks LDS to 76 KB so 2 blocks/CU overlap.
//
// Geometry: block = 4 waves (mg) x M_=4 m each, one d-half, one batch.
// x rows br=0..111 (x row R0+br, R0=32mb-40), 1KB each.
//   x ring: 64 rows (slot br&63), chunks of 8 rows, c=0..13.
//   filt ring: 12 rows (slot fr%12), chunks of 4 rows, c=0..10 (fr<=40).
// Phase p (p=0..9) = steps t=4p..4p+3, reads x rows [8p+7,8p+39] (chunks
// p..p+4) and filt rows 4p+2..4p+5 (chunks p,p+1).
//   stage at phase-p start (p<=8): x chunk p+5 (group (p+5)%8, disjoint
//   from read groups p..p+4; overwrites chunk p-3, last read phase p-3),
//   filt chunk p+2 (group (p+2)%3 vs reads p,p+1; overwrites chunk p-1).
//   DMA drained by end-of-phase-p barrier; first read in phase p+1.
// Prologue: x chunks 0..4 (40 rows) + filt chunks 0,1 (8 rows); sync.
// Tail: step t=40 (register-only: no pushes, filt row 40 via queue).
//
// Step semantics (refcheck'd since R4): t<=20: ae+=f*wE, ao+=f*wO;
// t>=21 swapped. E push br=8mg+2t+8; O push +1 (t<20) / -1 (t>20);
// O holds at t=20.
//
// Spill ledger: R2 no-unroll(64); R3 cap170 spill(84); R4 cap256 clean(128);
// R7 cap512 clean(256). R8 live ~110 -> lb(256,2) cap 128. Tell: FETCH GB.

#define B_ 32
#define T_ 2000
#define D_ 512
#define S_ 1000   // T/2
#define M_ 4      // m-positions per thread (=> 8 output rows)

#define FR_ 12                    // filt ring rows
#define FOFF 0                    // filt ring base (floats)
#define XOFF (FR_ * 256)          // x ring base (floats)
#define LDS_FLOATS (XOFF + 64 * 256)   // 76 KiB total

__device__ __forceinline__ float4 zf4() {
    float4 z; z.x = 0.f; z.y = 0.f; z.z = 0.f; z.w = 0.f; return z;
}

__device__ __forceinline__ void fma4(float4& a, const float4 f, const float4 w) {
    a.x = fmaf(f.x, w.x, a.x);
    a.y = fmaf(f.y, w.y, a.y);
    a.z = fmaf(f.z, w.z, a.z);
    a.w = fmaf(f.w, w.w, a.w);
}

// Async global->LDS DMA: 16B/lane x 64 lanes = one 1KB row per call.
__device__ __forceinline__ void gload_lds16(const float* g, float* l) {
    __builtin_amdgcn_global_load_lds(
        (const __attribute__((address_space(1))) void*)g,
        (__attribute__((address_space(3))) void*)l,
        16, 0, 0);
}

template<bool CHK>
__device__ __forceinline__ void fsmn_body(float* __restrict__ lds,
                                          const float* __restrict__ xb,
                                          const float* __restrict__ fb,
                                          float* __restrict__ ob,
                                          int m0, int R0, int lane, int mg)
{
    // ---- staging helpers (wave-uniform row index) ----
    auto stageX = [&](int br) {
        float* l = lds + XOFF + ((br & 63) << 8);
        const int xr = R0 + br;
        if (!CHK || (unsigned)xr < (unsigned)T_) {
            gload_lds16(xb + (size_t)xr * D_, l);     // xb already + lane*4
        } else {
            *(float4*)(l + lane * 4) = zf4();         // zero-fill pad rows
        }
    };
    auto stageF = [&](int fr) {
        if (fr <= 40)                                 // filt has 41 rows
            gload_lds16(fb + (size_t)fr * D_, lds + FOFF + ((fr % FR_) << 8));
    };
    // ---- LDS read helpers ----
    auto ldrow = [&](int br) -> float4 {              // x ring
        return *(const float4*)(lds + XOFF + ((br & 63) << 8) + lane * 4);
    };
    auto ldsF = [&](int t) -> float4 {                // filt ring (t compile-time)
        return *(const float4*)(lds + FOFF + ((t % FR_) << 8) + lane * 4);
    };

    // ---- Prologue: filt chunks 0,1 (rows 0..7) + x chunks 0..4 (rows 0..39) ----
#pragma unroll
    for (int k = 0; k < 2; ++k) stageF(4 * k + mg);
#pragma unroll
    for (int k = 0; k < 10; ++k) stageX(4 * k + mg);
    __syncthreads();                                  // all prologue DMA done

    // ---- Init windows (rows <= 31: chunks 0..3) + filter queue ----
    float4 wE[M_], wO[M_], ae[M_], ao[M_];
#pragma unroll
    for (int m = 0; m < M_; ++m) {
        wE[m] = ldrow(8 * mg + 2 * m);
        wO[m] = ldrow(8 * mg + 2 * m + 1);
        ae[m] = zf4(); ao[m] = zf4();
    }
    float4 qF0 = ldsF(0), qF1 = ldsF(1);              // dist-2 LDS queue

    // ---- One step (tap filt[t]); t compile-time under unroll ----
    auto dostep = [&](int t) {
        const float4 fv = qF0;
        qF0 = qF1;
        qF1 = (t + 2 <= 40) ? ldsF(t + 2) : zf4();
        if (t <= 20) {
#pragma unroll
            for (int m = 0; m < M_; ++m) { fma4(ae[m], fv, wE[m]); fma4(ao[m], fv, wO[m]); }
        } else {
#pragma unroll
            for (int m = 0; m < M_; ++m) { fma4(ao[m], fv, wE[m]); fma4(ae[m], fv, wO[m]); }
        }
        if (t < 40) {
#pragma unroll
            for (int m = 0; m < M_ - 1; ++m) wE[m] = wE[m + 1];
            wE[M_ - 1] = ldrow(8 * mg + 2 * t + 8);
            if (t != 20) {                            // O holds at junction
#pragma unroll
                for (int m = 0; m < M_ - 1; ++m) wO[m] = wO[m + 1];
                wO[M_ - 1] = ldrow(8 * mg + 2 * t + 8 + ((t < 20) ? 1 : -1));
            }
        }
    };

    // ---- Phases p=0..9 (4 steps each), then register-only tail t=40 ----
#pragma unroll
    for (int p = 0; p < 10; ++p) {
        if (p <= 8) {                                 // stage one phase ahead
            stageX(8 * (p + 5) + 2 * mg);             // x chunk p+5 (2 rows/wave)
            stageX(8 * (p + 5) + 2 * mg + 1);
            stageF(4 * (p + 2) + mg);                 // filt chunk p+2 (1 row/wave)
        }
#pragma unroll
        for (int t = 4 * p; t < 4 * p + 4; ++t) dostep(t);
        if (p < 9) __syncthreads();                   // drain DMA + fence reuse
    }
    dostep(40);

    // ---- Store 2*M_ output rows (coalesced float4 across 64 lanes) ----
#pragma unroll
    for (int m = 0; m < M_; ++m) {
        if (!CHK || (m0 + m) < S_) {
            *(float4*)(ob + (size_t)(2 * (m0 + m))     * D_) = ae[m];
            *(float4*)(ob + (size_t)(2 * (m0 + m) + 1) * D_) = ao[m];
        }
    }
}

__global__ __launch_bounds__(256, 2) void fsmn_kernel(
    const float* __restrict__ x, const float* __restrict__ filt,
    float* __restrict__ out)
{
    __shared__ float lds[LDS_FLOATS];      // 76 KiB: filt ring 12KB + x ring 64KB

    const int lane = threadIdx.x;          // 0..63
    const int mg   = threadIdx.y;          // 0..3 : m-group (one wave each)

    // XCD-chunked swizzle: 4032 blocks = 8 XCDs x 504 (bijective).
    const int bid  = blockIdx.x;
    const int xcd  = bid & 7;
    const int slot = bid >> 3;
    const int n    = xcd * 504 + slot;
    const int mb   = n % 63;               // 0..62 : m-block (16 m each)
    const int rest = n / 63;
    const int dh   = rest & 1;             // d-half
    const int b    = rest >> 1;            // batch

    const int m0b = mb * 16;
    const int m0  = m0b + mg * M_;
    const int d   = (dh * 64 + lane) * 4;
    const float* xb = x + (size_t)b * T_ * D_ + d;
    const float* fb = filt + d;
    float*       ob = out + (size_t)b * T_ * D_ + d;
    const int R0  = 2 * m0b - 40;          // x row of block-row 0

    // Interior iff all staged rows br=0..111 and all stores valid: mb in [2,60].
    // No early-return — all 256 threads reach every barrier.
    if (mb >= 2 && mb <= 60) fsmn_body<false>(lds, xb, fb, ob, m0, R0, lane, mg);
    else                     fsmn_body<true >(lds, xb, fb, ob, m0, R0, lane, mg);
}

extern "C" void kernel_launch(void* const* d_in, const int* in_sizes, int n_in,
                              void* d_out, int out_size, void* d_ws, size_t ws_size,
                              hipStream_t stream) {
    const float* x    = (const float*)d_in[0];
    const float* filt = (const float*)d_in[1];
    float*       out  = (float*)d_out;

    dim3 block(64, 4, 1);
    // 63 m-blocks x 2 d-halves x 32 batches = 4032 blocks.
    dim3 grid(4032, 1, 1);
    hipLaunchKernelGGL(fsmn_kernel, grid, block, 0, stream, x, filt, out);
}

// Round 9
// 297.380 us; speedup vs baseline: 1.9632x; 1.9632x over previous
//
#include <hip/hip_runtime.h>

// FSMN depthwise strided FIR — R9: R8's dual-ring structure + lb(256,1).
// B=32, T=2000, D=512, L=R=20, stride 2.
//
// R8 post-mortem: 454us REGRESSION. VGPR pinned at the lb(256,2) cap=128,
// WRITE 992MB / FETCH 680MB of scratch = the RA spilled the windows (the
// interleaved per-phase staging hoists ~27 global address pairs past R4's
// live set). R7's identical body was clean under lb(256,1) (chose 256).
// ALSO: the cap was pointless — 2 blocks/CU = 2 waves/SIMD needs only
// VGPR <= 256 (512 regs/SIMD-slot / 2), and LDS=76KB is the real limiter.
// R9 = R8 with lb(256,1). A/B: vs R7 isolates co-residency; vs R8 spill.
//
// Geometry (unchanged from R8, correctness verified absmax 0.125):
// block = 4 waves (mg) x M_=4 m each, one d-half, one batch.
// x rows br=0..111 (x row R0+br, R0=32mb-40), 1KB each.
//   x ring: 64 rows (slot br&63), chunks of 8 rows.
//   filt ring: 12 rows (slot fr%12), chunks of 4 rows (fr<=40).
// Phase p (0..9) = steps t=4p..4p+3, reads x chunks p..p+4, filt chunks
// p,p+1; stages x chunk p+5 and filt chunk p+2 at phase start (disjoint
// ring groups; overwritten chunks' reads ended >=1 phase ago; DMA drained
// by end-of-phase barrier, first read one phase later).
// Prologue: x chunks 0..4 + filt chunks 0,1; sync. Tail: t=40 reg-only.
//
// Step semantics (refcheck'd since R4): t<=20: ae+=f*wE, ao+=f*wO;
// t>=21 swapped. E push br=8mg+2t+8; O push +1 (t<20) / -1 (t>20);
// O holds at t=20.
//
// Spill ledger: R2 no-unroll(64); R3 cap170(84); R4 cap256 clean(128);
// R7 cap512 clean(256); R8 cap128 SPILL(128+992MB scratch). R9 cap512.

#define B_ 32
#define T_ 2000
#define D_ 512
#define S_ 1000   // T/2
#define M_ 4      // m-positions per thread (=> 8 output rows)

#define FR_ 12                    // filt ring rows
#define FOFF 0                    // filt ring base (floats)
#define XOFF (FR_ * 256)          // x ring base (floats)
#define LDS_FLOATS (XOFF + 64 * 256)   // 76 KiB total

__device__ __forceinline__ float4 zf4() {
    float4 z; z.x = 0.f; z.y = 0.f; z.z = 0.f; z.w = 0.f; return z;
}

__device__ __forceinline__ void fma4(float4& a, const float4 f, const float4 w) {
    a.x = fmaf(f.x, w.x, a.x);
    a.y = fmaf(f.y, w.y, a.y);
    a.z = fmaf(f.z, w.z, a.z);
    a.w = fmaf(f.w, w.w, a.w);
}

// Async global->LDS DMA: 16B/lane x 64 lanes = one 1KB row per call.
__device__ __forceinline__ void gload_lds16(const float* g, float* l) {
    __builtin_amdgcn_global_load_lds(
        (const __attribute__((address_space(1))) void*)g,
        (__attribute__((address_space(3))) void*)l,
        16, 0, 0);
}

template<bool CHK>
__device__ __forceinline__ void fsmn_body(float* __restrict__ lds,
                                          const float* __restrict__ xb,
                                          const float* __restrict__ fb,
                                          float* __restrict__ ob,
                                          int m0, int R0, int lane, int mg)
{
    // ---- staging helpers (wave-uniform row index) ----
    auto stageX = [&](int br) {
        float* l = lds + XOFF + ((br & 63) << 8);
        const int xr = R0 + br;
        if (!CHK || (unsigned)xr < (unsigned)T_) {
            gload_lds16(xb + (size_t)xr * D_, l);     // xb already + lane*4
        } else {
            *(float4*)(l + lane * 4) = zf4();         // zero-fill pad rows
        }
    };
    auto stageF = [&](int fr) {
        if (fr <= 40)                                 // filt has 41 rows
            gload_lds16(fb + (size_t)fr * D_, lds + FOFF + ((fr % FR_) << 8));
    };
    // ---- LDS read helpers ----
    auto ldrow = [&](int br) -> float4 {              // x ring
        return *(const float4*)(lds + XOFF + ((br & 63) << 8) + lane * 4);
    };
    auto ldsF = [&](int t) -> float4 {                // filt ring (t compile-time)
        return *(const float4*)(lds + FOFF + ((t % FR_) << 8) + lane * 4);
    };

    // ---- Prologue: filt chunks 0,1 (rows 0..7) + x chunks 0..4 (rows 0..39) ----
#pragma unroll
    for (int k = 0; k < 2; ++k) stageF(4 * k + mg);
#pragma unroll
    for (int k = 0; k < 10; ++k) stageX(4 * k + mg);
    __syncthreads();                                  // all prologue DMA done

    // ---- Init windows (rows <= 31: chunks 0..3) + filter queue ----
    float4 wE[M_], wO[M_], ae[M_], ao[M_];
#pragma unroll
    for (int m = 0; m < M_; ++m) {
        wE[m] = ldrow(8 * mg + 2 * m);
        wO[m] = ldrow(8 * mg + 2 * m + 1);
        ae[m] = zf4(); ao[m] = zf4();
    }
    float4 qF0 = ldsF(0), qF1 = ldsF(1);              // dist-2 LDS queue

    // ---- One step (tap filt[t]); t compile-time under unroll ----
    auto dostep = [&](int t) {
        const float4 fv = qF0;
        qF0 = qF1;
        qF1 = (t + 2 <= 40) ? ldsF(t + 2) : zf4();
        if (t <= 20) {
#pragma unroll
            for (int m = 0; m < M_; ++m) { fma4(ae[m], fv, wE[m]); fma4(ao[m], fv, wO[m]); }
        } else {
#pragma unroll
            for (int m = 0; m < M_; ++m) { fma4(ao[m], fv, wE[m]); fma4(ae[m], fv, wO[m]); }
        }
        if (t < 40) {
#pragma unroll
            for (int m = 0; m < M_ - 1; ++m) wE[m] = wE[m + 1];
            wE[M_ - 1] = ldrow(8 * mg + 2 * t + 8);
            if (t != 20) {                            // O holds at junction
#pragma unroll
                for (int m = 0; m < M_ - 1; ++m) wO[m] = wO[m + 1];
                wO[M_ - 1] = ldrow(8 * mg + 2 * t + 8 + ((t < 20) ? 1 : -1));
            }
        }
    };

    // ---- Phases p=0..9 (4 steps each), then register-only tail t=40 ----
#pragma unroll
    for (int p = 0; p < 10; ++p) {
        if (p <= 8) {                                 // stage one phase ahead
            stageX(8 * (p + 5) + 2 * mg);             // x chunk p+5 (2 rows/wave)
            stageX(8 * (p + 5) + 2 * mg + 1);
            stageF(4 * (p + 2) + mg);                 // filt chunk p+2 (1 row/wave)
        }
#pragma unroll
        for (int t = 4 * p; t < 4 * p + 4; ++t) dostep(t);
        if (p < 9) __syncthreads();                   // drain DMA + fence reuse
    }
    dostep(40);

    // ---- Store 2*M_ output rows (coalesced float4 across 64 lanes) ----
#pragma unroll
    for (int m = 0; m < M_; ++m) {
        if (!CHK || (m0 + m) < S_) {
            *(float4*)(ob + (size_t)(2 * (m0 + m))     * D_) = ae[m];
            *(float4*)(ob + (size_t)(2 * (m0 + m) + 1) * D_) = ao[m];
        }
    }
}

__global__ __launch_bounds__(256, 1) void fsmn_kernel(
    const float* __restrict__ x, const float* __restrict__ filt,
    float* __restrict__ out)
{
    __shared__ float lds[LDS_FLOATS];      // 76 KiB: filt ring 12KB + x ring 64KB

    const int lane = threadIdx.x;          // 0..63
    const int mg   = threadIdx.y;          // 0..3 : m-group (one wave each)

    // XCD-chunked swizzle: 4032 blocks = 8 XCDs x 504 (bijective).
    const int bid  = blockIdx.x;
    const int xcd  = bid & 7;
    const int slot = bid >> 3;
    const int n    = xcd * 504 + slot;
    const int mb   = n % 63;               // 0..62 : m-block (16 m each)
    const int rest = n / 63;
    const int dh   = rest & 1;             // d-half
    const int b    = rest >> 1;            // batch

    const int m0b = mb * 16;
    const int m0  = m0b + mg * M_;
    const int d   = (dh * 64 + lane) * 4;
    const float* xb = x + (size_t)b * T_ * D_ + d;
    const float* fb = filt + d;
    float*       ob = out + (size_t)b * T_ * D_ + d;
    const int R0  = 2 * m0b - 40;          // x row of block-row 0

    // Interior iff all staged rows br=0..111 and all stores valid: mb in [2,60].
    // No early-return — all 256 threads reach every barrier.
    if (mb >= 2 && mb <= 60) fsmn_body<false>(lds, xb, fb, ob, m0, R0, lane, mg);
    else                     fsmn_body<true >(lds, xb, fb, ob, m0, R0, lane, mg);
}

extern "C" void kernel_launch(void* const* d_in, const int* in_sizes, int n_in,
                              void* d_out, int out_size, void* d_ws, size_t ws_size,
                              hipStream_t stream) {
    const float* x    = (const float*)d_in[0];
    const float* filt = (const float*)d_in[1];
    float*       out  = (float*)d_out;

    dim3 block(64, 4, 1);
    // 63 m-blocks x 2 d-halves x 32 batches = 4032 blocks.
    dim3 grid(4032, 1, 1);
    hipLaunchKernelGGL(fsmn_kernel, grid, block, 0, stream, x, filt, out);
}